// Round 6
// baseline (373.920 us; speedup 1.0000x reference)
//
#include <hip/hip_runtime.h>
#include <hip/hip_bf16.h>

// out[b,i,k] = sum_j tanh(bn2( relu(bn1( [x_i,x_j,adj_ij] @ W1 )) @ W2 ))[k]
// Phase-1: acc = P1[h] + adj@W1a (MFMA K=16 pad 32); epilogue += P2 (bf16 LDS), relu -> h1b
// Phase-2: h1b @ W2f (register frags); tanh via exp2/rcp (2log2e folded)
// Staging: register-staged (global->reg in phase-1 slot, reg->LDS after barrier B)

typedef short short8 __attribute__((ext_vector_type(8)));
typedef float f32x4 __attribute__((ext_vector_type(4)));

#define EPSV 1e-5f
#define TWO_LOG2E 2.885390081777927f

// ws float offsets
#define OFF_P1T  0         // [1024][256] f32
#define OFF_P2I  262144    // bf16 image [2][8][64][256], &15-swizzled cols (131072 floats)
#define OFF_S1   393216
#define OFF_T1   393472
#define OFF_T2   393728    // t2 * 2log2e
#define OFF_W1F  393984    // bf16 frags [16][64][8] = 8192 shorts = 4096 floats
#define OFF_W2F  398080    // bf16 frags [128][64][8] = 65536 shorts = 32768 floats

__device__ __forceinline__ short f2bf(float f) {
    unsigned u = __builtin_bit_cast(unsigned, f);
    u += 0x7fffu + ((u >> 16) & 1u);
    return (short)(u >> 16);
}

__device__ __forceinline__ float bf2f(short s) {
    unsigned u = ((unsigned)(unsigned short)s) << 16;
    return __builtin_bit_cast(float, u);
}

__device__ __forceinline__ unsigned pk2bf(float lo, float hi) {
    unsigned u;
    asm("v_cvt_pk_bf16_f32 %0, %1, %2" : "=v"(u) : "v"(lo), "v"(hi));
    return u;
}

__global__ void prep_scalars(const float* __restrict__ g1, const float* __restrict__ b1,
                             const float* __restrict__ m1, const float* __restrict__ v1,
                             const float* __restrict__ g2, const float* __restrict__ b2,
                             const float* __restrict__ m2, const float* __restrict__ v2,
                             float* __restrict__ wsf) {
    int t = threadIdx.x;  // h (0..255)
    float s1 = g1[t] * __frsqrt_rn(v1[t] + EPSV);
    float t1 = b1[t] - m1[t] * s1;
    float s2 = g2[t] * __frsqrt_rn(v2[t] + EPSV);
    float t2 = b2[t] - m2[t] * s2;
    wsf[OFF_S1 + t] = s1;
    wsf[OFF_T1 + t] = t1;
    wsf[OFF_T2 + t] = t2 * TWO_LOG2E;
}

// W1a fragments [16][64][8]: frag f = w*2+n, lane l: col=(f>>1)*32+(f&1)*16+(l&15),
// k = (l>>4)*8+e (k<16 real, else 0), val = W1[(256+k)*256+col]*s1[col]
__global__ void prep_w1f(const float* __restrict__ W1, float* __restrict__ wsf) {
    int tid = blockIdx.x * 256 + threadIdx.x;  // 0..1023
    int f = tid >> 6, l = tid & 63;
    int col = (f >> 1) * 32 + (f & 1) * 16 + (l & 15);
    int kb = (l >> 4) * 8;
    float s1 = wsf[OFF_S1 + col];
    short8 v;
#pragma unroll
    for (int e = 0; e < 8; ++e) {
        int k = kb + e;
        v[e] = (k < 16) ? f2bf(W1[(256 + k) * 256 + col] * s1) : (short)0;
    }
    *(short8*)((short*)(wsf + OFF_W1F) + tid * 8) = v;
}

// W2 fragments [128][64][8]: frag f = w*16+n*8+s, lane l: col = w*32+n*16+(l&15),
// k = s*32+(l>>4)*8+e, val = W2[k*256+col]*s2[col]*2log2e
__global__ void prep_w2f(const float* __restrict__ W2,
                         const float* __restrict__ g2, const float* __restrict__ v2,
                         float* __restrict__ wsf) {
    int tid = blockIdx.x * 256 + threadIdx.x;  // 0..8191
    int f = tid >> 6, l = tid & 63;
    int w = f >> 4, n = (f >> 3) & 1, s = f & 7;
    int col = w * 32 + n * 16 + (l & 15);
    int kb = s * 32 + (l >> 4) * 8;
    float s2 = g2[col] * __frsqrt_rn(v2[col] + EPSV) * TWO_LOG2E;
    short8 v;
#pragma unroll
    for (int e = 0; e < 8; ++e)
        v[e] = f2bf(W2[(kb + e) * 256 + col] * s2);
    *(short8*)((short*)(wsf + OFF_W2F) + tid * 8) = v;
}

// P1t f32 + P2 bf16 swizzled image [b][jt][row][h ^ ((row&15)<<3)]
__global__ void prep_p(const float* __restrict__ inp, const float* __restrict__ W1,
                       float* __restrict__ wsf) {
    int bn = blockIdx.x, h = threadIdx.x;
    const float* x = inp + (size_t)bn * 128;
    float a1 = 0.f, a2 = 0.f;
    for (int c = 0; c < 128; ++c) {
        float xv = x[c];
        a1 = fmaf(xv, W1[c * 256 + h], a1);
        a2 = fmaf(xv, W1[(128 + c) * 256 + h], a2);
    }
    float s1 = wsf[OFF_S1 + h], t1 = wsf[OFF_T1 + h];
    wsf[OFF_P1T + (size_t)bn * 256 + h] = a1 * s1 + t1;
    int b = bn >> 9, j = bn & 511, jt = j >> 6, row = j & 63;
    short* img = (short*)(wsf + OFF_P2I);
    img[(((b * 8 + jt) * 64 + row) << 8) + (h ^ ((row & 15) << 3))] = f2bf(a2 * s1);
}

__global__ __launch_bounds__(512, 4) void propmain(
    const float* __restrict__ adj, const float* __restrict__ wsf,
    float* __restrict__ out) {
    __shared__ __align__(16) short h1b[64 * 256];   // bf16 H1, &15-swizzled (32 KB)
    __shared__ __align__(16) short p2b[64 * 256];   // bf16 P2 tile, &15-swizzled (32 KB)
    __shared__ __align__(16) short adjbf[64 * 32];  // bf16 adj tile, chunk-XOR (4 KB)

    const int bi = blockIdx.x;
    const int b = bi >> 9;
    const int t = threadIdx.x;
    const int w = t >> 6, l = t & 63, r = l & 15, q = l >> 4;

    const float* P1t = wsf + OFF_P1T;
    const float* t2p = wsf + OFF_T2;
    const short* W1f = (const short*)(wsf + OFF_W1F);
    const short* W2f = (const short*)(wsf + OFF_W2F);
    const short* p2img = (const short*)(wsf + OFF_P2I) + ((size_t)b << 17);
    const float* adjbase = adj + (size_t)bi * 512 * 16;

    // persistent register fragments: W2 slice for this wave (64 VGPR)
    short8 bB2[2][8];
    float t2v[2], p1v[2];
#pragma unroll
    for (int n = 0; n < 2; ++n) {
#pragma unroll
        for (int s = 0; s < 8; ++s)
            bB2[n][s] = *(const short8*)(W2f + ((w * 16 + n * 8 + s) * 64 + l) * 8);
        const int hc = w * 32 + n * 16 + r;
        t2v[n] = t2p[hc];
        p1v[n] = P1t[(size_t)bi * 256 + hc];
    }

    // per-thread staging constants
    const int arow_st = t >> 3, ks_st = (t & 7) * 2;
    const int aslot = arow_st * 32 + (((ks_st >> 3) ^ (arow_st & 3)) << 3) + (ks_st & 7);
    const short* p2src = p2img + w * 2048 + l * 8;  // + jt*16384 + k*512
    short* p2dst = p2b + w * 2048 + l * 8;          // + k*512

    // staging registers
    short8 stp[4];
    unsigned stadj;

#define LOAD_TILE(JT) do {                                                    \
        const int _jt = (JT);                                                 \
        _Pragma("unroll")                                                     \
        for (int k = 0; k < 4; ++k)                                           \
            stp[k] = *(const short8*)(p2src + _jt * 16384 + k * 512);         \
        const float2 _av = *(const float2*)(adjbase + _jt * 1024 + t * 2);    \
        stadj = pk2bf(_av.x, _av.y);                                          \
    } while (0)

#define WRITE_TILE() do {                                                     \
        _Pragma("unroll")                                                     \
        for (int k = 0; k < 4; ++k)                                           \
            *(short8*)(p2dst + k * 512) = stp[k];                             \
        *(unsigned*)(adjbf + aslot) = stadj;                                  \
    } while (0)

    // zero adjbf pads (bijective chunk-XOR: pad chunks never touched by data writes)
    if (t < 256) {
        short8 z = {0, 0, 0, 0, 0, 0, 0, 0};
        *(short8*)(adjbf + t * 8) = z;
    }
    LOAD_TILE(0);
    __syncthreads();   // zero visible before data writes to adjbf
    WRITE_TILE();

    float part[2] = {0.f, 0.f};

    for (int jt = 0; jt < 8; ++jt) {
        __syncthreads();  // (A) staged tile jt visible

        if (jt < 7) LOAD_TILE(jt + 1);  // global->reg, hides under phase 1

        // ---- phase 1: acc = P1 + adj@W1a (MFMA); epilogue += P2, relu -> h1b ----
        const short* w1fw = W1f + (w * 2) * 512 + l * 8;
        const short8 bB1_0 = *(const short8*)(w1fw);
        const short8 bB1_1 = *(const short8*)(w1fw + 512);
#pragma unroll
        for (int rf = 0; rf < 4; ++rf) {
            const int arow = rf * 16 + r;
            const short8 aA1 = *(const short8*)(adjbf + arow * 32 + (q ^ (r & 3)) * 8);
            f32x4 a0 = {p1v[0], p1v[0], p1v[0], p1v[0]};
            f32x4 a1 = {p1v[1], p1v[1], p1v[1], p1v[1]};
            a0 = __builtin_amdgcn_mfma_f32_16x16x32_bf16(aA1, bB1_0, a0, 0, 0, 0);
            a1 = __builtin_amdgcn_mfma_f32_16x16x32_bf16(aA1, bB1_1, a1, 0, 0, 0);
#pragma unroll
            for (int n = 0; n < 2; ++n) {
                const f32x4 av = n ? a1 : a0;
                const int colb = w * 32 + n * 16 + r;
#pragma unroll
                for (int e = 0; e < 4; ++e) {
                    const int row2 = rf * 16 + q * 4 + e;
                    const int slot = (row2 << 8) + (colb ^ ((row2 & 15) << 3));
                    const float y = fmaxf(av[e] + bf2f(p2b[slot]), 0.f);
                    h1b[slot] = f2bf(y);
                }
            }
        }
        __syncthreads();  // (B) h1b visible; p2b/adjbf reads of tile jt done

        if (jt < 7) WRITE_TILE();  // reg->LDS for tile jt+1 (disjoint from h1b)

        // ---- phase 2: h1b @ W2f (register frags), tanh partial sums ----
#pragma unroll
        for (int hf = 0; hf < 2; ++hf) {
            f32x4 acc[2][2];
#pragma unroll
            for (int rr = 0; rr < 2; ++rr)
#pragma unroll
                for (int n = 0; n < 2; ++n)
                    acc[rr][n] = (f32x4){t2v[n], t2v[n], t2v[n], t2v[n]};
#pragma unroll
            for (int s = 0; s < 8; ++s) {
#pragma unroll
                for (int rr = 0; rr < 2; ++rr) {
                    const int row = (hf * 2 + rr) * 16 + r;
                    const short8 aA = *(const short8*)(
                        h1b + (row << 8) + ((s * 32 + q * 8) ^ ((row & 15) << 3)));
                    acc[rr][0] = __builtin_amdgcn_mfma_f32_16x16x32_bf16(
                        aA, bB2[0][s], acc[rr][0], 0, 0, 0);
                    acc[rr][1] = __builtin_amdgcn_mfma_f32_16x16x32_bf16(
                        aA, bB2[1][s], acc[rr][1], 0, 0, 0);
                }
            }
#pragma unroll
            for (int n = 0; n < 2; ++n) {
                float ps = 0.f;
#pragma unroll
                for (int rr = 0; rr < 2; ++rr)
#pragma unroll
                    for (int e = 0; e < 4; ++e) {
                        const float ex = exp2f(acc[rr][n][e]);
                        ps += __builtin_amdgcn_rcpf(ex + 1.f);
                    }
                part[n] += ps;
            }
        }
    }

    // sum_j tanh = 512 - 2*sum(rcp); reduce over q
#pragma unroll
    for (int n = 0; n < 2; ++n) {
        float v = part[n];
        v += __shfl_xor(v, 16, 64);
        v += __shfl_xor(v, 32, 64);
        if (q == 0) out[(size_t)bi * 256 + w * 32 + n * 16 + r] = 512.f - 2.f * v;
    }
#undef LOAD_TILE
#undef WRITE_TILE
}

extern "C" void kernel_launch(void* const* d_in, const int* in_sizes, int n_in,
                              void* d_out, int out_size, void* d_ws, size_t ws_size,
                              hipStream_t stream) {
    (void)in_sizes; (void)n_in; (void)out_size; (void)ws_size;
    const float* inputs = (const float*)d_in[0];
    const float* adj    = (const float*)d_in[1];
    const float* W1     = (const float*)d_in[2];
    const float* g1     = (const float*)d_in[3];
    const float* b1     = (const float*)d_in[4];
    const float* m1     = (const float*)d_in[5];
    const float* v1     = (const float*)d_in[6];
    const float* W2     = (const float*)d_in[7];
    const float* g2     = (const float*)d_in[8];
    const float* b2     = (const float*)d_in[9];
    const float* m2     = (const float*)d_in[10];
    const float* v2     = (const float*)d_in[11];
    float* out = (float*)d_out;
    float* wsf = (float*)d_ws;

    prep_scalars<<<1, 256, 0, stream>>>(g1, b1, m1, v1, g2, b2, m2, v2, wsf);
    prep_w1f<<<4, 256, 0, stream>>>(W1, wsf);
    prep_w2f<<<32, 256, 0, stream>>>(W2, g2, v2, wsf);
    prep_p<<<1024, 256, 0, stream>>>(inputs, W1, wsf);
    propmain<<<1024, 512, 0, stream>>>(adj, wsf, out);
}

// Round 7
// 372.759 us; speedup vs baseline: 1.0031x; 1.0031x over previous
//
#include <hip/hip_runtime.h>
#include <hip/hip_bf16.h>

// out[b,i,k] = sum_j tanh(bn2( relu(bn1( [x_i,x_j,adj_ij] @ W1 )) @ W2 ))[k]
// Phase-1: acc = P1[h] + adj@W1a (MFMA K=16 pad 32); epilogue += P2 (bf16 LDS), relu -> h1b
// Phase-2: h1b @ W2f (register frags); tanh via exp2/rcp (2log2e folded)
// Staging: P2 via global_load_lds (pre-swizzled image, linear copy); adj reg-staged.

typedef short short8 __attribute__((ext_vector_type(8)));
typedef float f32x4 __attribute__((ext_vector_type(4)));

#define EPSV 1e-5f
#define TWO_LOG2E 2.885390081777927f

// ws float offsets
#define OFF_P1T  0         // [1024][256] f32
#define OFF_P2I  262144    // bf16 image [2][8][64][256], &15-swizzled cols (131072 floats)
#define OFF_S1   393216
#define OFF_T1   393472
#define OFF_T2   393728    // t2 * 2log2e
#define OFF_W1F  393984    // bf16 frags [16][64][8] = 8192 shorts = 4096 floats
#define OFF_W2F  398080    // bf16 frags [128][64][8] = 65536 shorts = 32768 floats

__device__ __forceinline__ short f2bf(float f) {
    unsigned u = __builtin_bit_cast(unsigned, f);
    u += 0x7fffu + ((u >> 16) & 1u);
    return (short)(u >> 16);
}

__device__ __forceinline__ float bf2f(short s) {
    unsigned u = ((unsigned)(unsigned short)s) << 16;
    return __builtin_bit_cast(float, u);
}

__device__ __forceinline__ unsigned pk2bf(float lo, float hi) {
    unsigned u;
    asm("v_cvt_pk_bf16_f32 %0, %1, %2" : "=v"(u) : "v"(lo), "v"(hi));
    return u;
}

__global__ void prep_scalars(const float* __restrict__ g1, const float* __restrict__ b1,
                             const float* __restrict__ m1, const float* __restrict__ v1,
                             const float* __restrict__ g2, const float* __restrict__ b2,
                             const float* __restrict__ m2, const float* __restrict__ v2,
                             float* __restrict__ wsf) {
    int t = threadIdx.x;  // h (0..255)
    float s1 = g1[t] * __frsqrt_rn(v1[t] + EPSV);
    float t1 = b1[t] - m1[t] * s1;
    float s2 = g2[t] * __frsqrt_rn(v2[t] + EPSV);
    float t2 = b2[t] - m2[t] * s2;
    wsf[OFF_S1 + t] = s1;
    wsf[OFF_T1 + t] = t1;
    wsf[OFF_T2 + t] = t2 * TWO_LOG2E;
}

// W1a fragments [16][64][8]: frag f = w*2+n, lane l: col=(f>>1)*32+(f&1)*16+(l&15),
// k = (l>>4)*8+e (k<16 real, else 0), val = W1[(256+k)*256+col]*s1[col]
__global__ void prep_w1f(const float* __restrict__ W1, float* __restrict__ wsf) {
    int tid = blockIdx.x * 256 + threadIdx.x;  // 0..1023
    int f = tid >> 6, l = tid & 63;
    int col = (f >> 1) * 32 + (f & 1) * 16 + (l & 15);
    int kb = (l >> 4) * 8;
    float s1 = wsf[OFF_S1 + col];
    short8 v;
#pragma unroll
    for (int e = 0; e < 8; ++e) {
        int k = kb + e;
        v[e] = (k < 16) ? f2bf(W1[(256 + k) * 256 + col] * s1) : (short)0;
    }
    *(short8*)((short*)(wsf + OFF_W1F) + tid * 8) = v;
}

// W2 fragments [128][64][8]: frag f = w*16+n*8+s, lane l: col = w*32+n*16+(l&15),
// k = s*32+(l>>4)*8+e, val = W2[k*256+col]*s2[col]*2log2e
__global__ void prep_w2f(const float* __restrict__ W2,
                         const float* __restrict__ g2, const float* __restrict__ v2,
                         float* __restrict__ wsf) {
    int tid = blockIdx.x * 256 + threadIdx.x;  // 0..8191
    int f = tid >> 6, l = tid & 63;
    int w = f >> 4, n = (f >> 3) & 1, s = f & 7;
    int col = w * 32 + n * 16 + (l & 15);
    int kb = s * 32 + (l >> 4) * 8;
    float s2 = g2[col] * __frsqrt_rn(v2[col] + EPSV) * TWO_LOG2E;
    short8 v;
#pragma unroll
    for (int e = 0; e < 8; ++e)
        v[e] = f2bf(W2[(kb + e) * 256 + col] * s2);
    *(short8*)((short*)(wsf + OFF_W2F) + tid * 8) = v;
}

// P1t f32 + P2 bf16 swizzled image [b][jt][row][h ^ ((row&15)<<3)]
__global__ void prep_p(const float* __restrict__ inp, const float* __restrict__ W1,
                       float* __restrict__ wsf) {
    int bn = blockIdx.x, h = threadIdx.x;
    const float* x = inp + (size_t)bn * 128;
    float a1 = 0.f, a2 = 0.f;
    for (int c = 0; c < 128; ++c) {
        float xv = x[c];
        a1 = fmaf(xv, W1[c * 256 + h], a1);
        a2 = fmaf(xv, W1[(128 + c) * 256 + h], a2);
    }
    float s1 = wsf[OFF_S1 + h], t1 = wsf[OFF_T1 + h];
    wsf[OFF_P1T + (size_t)bn * 256 + h] = a1 * s1 + t1;
    int b = bn >> 9, j = bn & 511, jt = j >> 6, row = j & 63;
    short* img = (short*)(wsf + OFF_P2I);
    img[(((b * 8 + jt) * 64 + row) << 8) + (h ^ ((row & 15) << 3))] = f2bf(a2 * s1);
}

__global__ __launch_bounds__(512, 4) void propmain(
    const float* __restrict__ adj, const float* __restrict__ wsf,
    float* __restrict__ out) {
    __shared__ __align__(16) short h1b[64 * 256];   // bf16 H1, &15-swizzled (32 KB)
    __shared__ __align__(16) short p2b[64 * 256];   // bf16 P2 tile, &15-swizzled (32 KB)
    __shared__ __align__(16) short adjbf[64 * 32];  // bf16 adj tile, chunk-XOR (4 KB)

    const int bi = blockIdx.x;
    const int b = bi >> 9;
    const int t = threadIdx.x;
    const int w = t >> 6, l = t & 63, r = l & 15, q = l >> 4;

    const float* P1t = wsf + OFF_P1T;
    const float* t2p = wsf + OFF_T2;
    const short* W1f = (const short*)(wsf + OFF_W1F);
    const short* W2f = (const short*)(wsf + OFF_W2F);
    const short* p2img = (const short*)(wsf + OFF_P2I) + ((size_t)b << 17);
    const float* adjbase = adj + (size_t)bi * 512 * 16;

    // persistent register fragments: W2 slice for this wave (64 VGPR)
    short8 bB2[2][8];
    float t2v[2], p1v[2];
#pragma unroll
    for (int n = 0; n < 2; ++n) {
#pragma unroll
        for (int s = 0; s < 8; ++s)
            bB2[n][s] = *(const short8*)(W2f + ((w * 16 + n * 8 + s) * 64 + l) * 8);
        const int hc = w * 32 + n * 16 + r;
        t2v[n] = t2p[hc];
        p1v[n] = P1t[(size_t)bi * 256 + hc];
    }

    // staging constants
    const int arow_st = t >> 3, ks_st = (t & 7) * 2;
    const int aslot = arow_st * 32 + (((ks_st >> 3) ^ (arow_st & 3)) << 3) + (ks_st & 7);
    // gload_lds: LDS dst wave-uniform (w,k); global src per-lane (+l*8)
    const short* p2src = p2img + w * 2048 + l * 8;  // + jt*16384 + k*512

    unsigned stadj;

#define STAGE_P2(JT) do {                                                       \
        const int _jt = (JT);                                                   \
        _Pragma("unroll")                                                       \
        for (int k = 0; k < 4; ++k)                                             \
            __builtin_amdgcn_global_load_lds(                                   \
                (const __attribute__((address_space(1))) unsigned*)             \
                    (p2src + _jt * 16384 + k * 512),                            \
                (__attribute__((address_space(3))) unsigned*)                   \
                    (p2b + w * 2048 + k * 512),                                 \
                16, 0, 0);                                                      \
    } while (0)

#define LOAD_ADJ(JT) do {                                                       \
        const float2 _av = *(const float2*)(adjbase + (JT) * 1024 + t * 2);     \
        stadj = pk2bf(_av.x, _av.y);                                            \
    } while (0)

    // prologue: zero adjbf pads, stage tile 0
    if (t < 256) {
        short8 z = {0, 0, 0, 0, 0, 0, 0, 0};
        *(short8*)(adjbf + t * 8) = z;
    }
    STAGE_P2(0);
    LOAD_ADJ(0);
    __syncthreads();   // zeros visible before adj data writes
    *(unsigned*)(adjbf + aslot) = stadj;

    float part[2] = {0.f, 0.f};

    for (int jt = 0; jt < 8; ++jt) {
        __syncthreads();  // (A) vmcnt(0) drain: p2b landed; adjbf writes visible

        if (jt < 7) LOAD_ADJ(jt + 1);  // global->reg, hides under phase 1

        // ---- phase 1: acc = P1 + adj@W1a (MFMA); epilogue += P2, relu -> h1b ----
        const short* w1fw = W1f + (w * 2) * 512 + l * 8;
        const short8 bB1_0 = *(const short8*)(w1fw);
        const short8 bB1_1 = *(const short8*)(w1fw + 512);
#pragma unroll
        for (int rf = 0; rf < 4; ++rf) {
            const int arow = rf * 16 + r;
            const short8 aA1 = *(const short8*)(adjbf + arow * 32 + (q ^ (r & 3)) * 8);
            f32x4 a0 = {p1v[0], p1v[0], p1v[0], p1v[0]};
            f32x4 a1 = {p1v[1], p1v[1], p1v[1], p1v[1]};
            a0 = __builtin_amdgcn_mfma_f32_16x16x32_bf16(aA1, bB1_0, a0, 0, 0, 0);
            a1 = __builtin_amdgcn_mfma_f32_16x16x32_bf16(aA1, bB1_1, a1, 0, 0, 0);
#pragma unroll
            for (int n = 0; n < 2; ++n) {
                const f32x4 av = n ? a1 : a0;
                const int colb = w * 32 + n * 16 + r;
#pragma unroll
                for (int e = 0; e < 4; ++e) {
                    const int row2 = rf * 16 + q * 4 + e;
                    const int slot = (row2 << 8) + (colb ^ ((row2 & 15) << 3));
                    const float y = fmaxf(av[e] + bf2f(p2b[slot]), 0.f);
                    h1b[slot] = f2bf(y);
                }
            }
        }
        __syncthreads();  // (B) h1b visible; p2b/adjbf reads of tile jt done

        if (jt < 7) {
            STAGE_P2(jt + 1);                    // async into p2b, flies over phase 2
            *(unsigned*)(adjbf + aslot) = stadj; // adj tile jt+1
        }

        // ---- phase 2: h1b @ W2f (register frags), tanh partial sums ----
#pragma unroll
        for (int hf = 0; hf < 2; ++hf) {
            f32x4 acc[2][2];
#pragma unroll
            for (int rr = 0; rr < 2; ++rr)
#pragma unroll
                for (int n = 0; n < 2; ++n)
                    acc[rr][n] = (f32x4){t2v[n], t2v[n], t2v[n], t2v[n]};
#pragma unroll
            for (int s = 0; s < 8; ++s) {
#pragma unroll
                for (int rr = 0; rr < 2; ++rr) {
                    const int row = (hf * 2 + rr) * 16 + r;
                    const short8 aA = *(const short8*)(
                        h1b + (row << 8) + ((s * 32 + q * 8) ^ ((row & 15) << 3)));
                    acc[rr][0] = __builtin_amdgcn_mfma_f32_16x16x32_bf16(
                        aA, bB2[0][s], acc[rr][0], 0, 0, 0);
                    acc[rr][1] = __builtin_amdgcn_mfma_f32_16x16x32_bf16(
                        aA, bB2[1][s], acc[rr][1], 0, 0, 0);
                }
            }
#pragma unroll
            for (int n = 0; n < 2; ++n) {
                float ps = 0.f;
#pragma unroll
                for (int rr = 0; rr < 2; ++rr)
#pragma unroll
                    for (int e = 0; e < 4; ++e) {
                        const float ex = exp2f(acc[rr][n][e]);
                        ps += __builtin_amdgcn_rcpf(ex + 1.f);
                    }
                part[n] += ps;
            }
        }
    }

    // sum_j tanh = 512 - 2*sum(rcp); reduce over q
#pragma unroll
    for (int n = 0; n < 2; ++n) {
        float v = part[n];
        v += __shfl_xor(v, 16, 64);
        v += __shfl_xor(v, 32, 64);
        if (q == 0) out[(size_t)bi * 256 + w * 32 + n * 16 + r] = 512.f - 2.f * v;
    }
#undef STAGE_P2
#undef LOAD_ADJ
}

extern "C" void kernel_launch(void* const* d_in, const int* in_sizes, int n_in,
                              void* d_out, int out_size, void* d_ws, size_t ws_size,
                              hipStream_t stream) {
    (void)in_sizes; (void)n_in; (void)out_size; (void)ws_size;
    const float* inputs = (const float*)d_in[0];
    const float* adj    = (const float*)d_in[1];
    const float* W1     = (const float*)d_in[2];
    const float* g1     = (const float*)d_in[3];
    const float* b1     = (const float*)d_in[4];
    const float* m1     = (const float*)d_in[5];
    const float* v1     = (const float*)d_in[6];
    const float* W2     = (const float*)d_in[7];
    const float* g2     = (const float*)d_in[8];
    const float* b2     = (const float*)d_in[9];
    const float* m2     = (const float*)d_in[10];
    const float* v2     = (const float*)d_in[11];
    float* out = (float*)d_out;
    float* wsf = (float*)d_ws;

    prep_scalars<<<1, 256, 0, stream>>>(g1, b1, m1, v1, g2, b2, m2, v2, wsf);
    prep_w1f<<<4, 256, 0, stream>>>(W1, wsf);
    prep_w2f<<<32, 256, 0, stream>>>(W2, g2, v2, wsf);
    prep_p<<<1024, 256, 0, stream>>>(inputs, W1, wsf);
    propmain<<<1024, 512, 0, stream>>>(adj, wsf, out);
}

// Round 8
// 141.226 us; speedup vs baseline: 2.6477x; 2.6395x over previous
//
#include <hip/hip_runtime.h>
#include <hip/hip_bf16.h>

// out[b,i,k] = sum_j tanh(bn2( relu(bn1( [x_i,x_j,adj_ij] @ W1 )) @ W2 ))[k]
// Phase-1: acc = P1[h] + adj@W1a (MFMA K=16 pad 32); epilogue += P2 (bf16 LDS), relu -> h1b
// Phase-2: h1b @ W2 frags loaded per s-step from L2 (blinded ptr, no persistent regs)
// Staging: P2 via global_load_lds (pre-swizzled image); adj reg-staged.

typedef short short8 __attribute__((ext_vector_type(8)));
typedef float f32x4 __attribute__((ext_vector_type(4)));

#define EPSV 1e-5f
#define TWO_LOG2E 2.885390081777927f

// ws float offsets
#define OFF_P1T  0         // [1024][256] f32
#define OFF_P2I  262144    // bf16 image [2][8][64][256], &15-swizzled cols (131072 floats)
#define OFF_S1   393216
#define OFF_T1   393472
#define OFF_T2   393728    // t2 * 2log2e
#define OFF_W1F  393984    // bf16 frags [16][64][8] = 8192 shorts = 4096 floats
#define OFF_W2F  398080    // bf16 frags [128][64][8] = 65536 shorts = 32768 floats

__device__ __forceinline__ short f2bf(float f) {
    unsigned u = __builtin_bit_cast(unsigned, f);
    u += 0x7fffu + ((u >> 16) & 1u);
    return (short)(u >> 16);
}

__device__ __forceinline__ float bf2f(short s) {
    unsigned u = ((unsigned)(unsigned short)s) << 16;
    return __builtin_bit_cast(float, u);
}

__device__ __forceinline__ unsigned pk2bf(float lo, float hi) {
    unsigned u;
    asm("v_cvt_pk_bf16_f32 %0, %1, %2" : "=v"(u) : "v"(lo), "v"(hi));
    return u;
}

__global__ void prep_scalars(const float* __restrict__ g1, const float* __restrict__ b1,
                             const float* __restrict__ m1, const float* __restrict__ v1,
                             const float* __restrict__ g2, const float* __restrict__ b2,
                             const float* __restrict__ m2, const float* __restrict__ v2,
                             float* __restrict__ wsf) {
    int t = threadIdx.x;  // h (0..255)
    float s1 = g1[t] * __frsqrt_rn(v1[t] + EPSV);
    float t1 = b1[t] - m1[t] * s1;
    float s2 = g2[t] * __frsqrt_rn(v2[t] + EPSV);
    float t2 = b2[t] - m2[t] * s2;
    wsf[OFF_S1 + t] = s1;
    wsf[OFF_T1 + t] = t1;
    wsf[OFF_T2 + t] = t2 * TWO_LOG2E;
}

// W1a fragments [16][64][8]: frag f = w*2+n, lane l: col=(f>>1)*32+(f&1)*16+(l&15),
// k = (l>>4)*8+e (k<16 real, else 0), val = W1[(256+k)*256+col]*s1[col]
__global__ void prep_w1f(const float* __restrict__ W1, float* __restrict__ wsf) {
    int tid = blockIdx.x * 256 + threadIdx.x;  // 0..1023
    int f = tid >> 6, l = tid & 63;
    int col = (f >> 1) * 32 + (f & 1) * 16 + (l & 15);
    int kb = (l >> 4) * 8;
    float s1 = wsf[OFF_S1 + col];
    short8 v;
#pragma unroll
    for (int e = 0; e < 8; ++e) {
        int k = kb + e;
        v[e] = (k < 16) ? f2bf(W1[(256 + k) * 256 + col] * s1) : (short)0;
    }
    *(short8*)((short*)(wsf + OFF_W1F) + tid * 8) = v;
}

// W2 fragments [128][64][8]: frag f = w*16+n*8+s, lane l: col = w*32+n*16+(l&15),
// k = s*32+(l>>4)*8+e, val = W2[k*256+col]*s2[col]*2log2e
__global__ void prep_w2f(const float* __restrict__ W2,
                         const float* __restrict__ g2, const float* __restrict__ v2,
                         float* __restrict__ wsf) {
    int tid = blockIdx.x * 256 + threadIdx.x;  // 0..8191
    int f = tid >> 6, l = tid & 63;
    int w = f >> 4, n = (f >> 3) & 1, s = f & 7;
    int col = w * 32 + n * 16 + (l & 15);
    int kb = s * 32 + (l >> 4) * 8;
    float s2 = g2[col] * __frsqrt_rn(v2[col] + EPSV) * TWO_LOG2E;
    short8 v;
#pragma unroll
    for (int e = 0; e < 8; ++e)
        v[e] = f2bf(W2[(kb + e) * 256 + col] * s2);
    *(short8*)((short*)(wsf + OFF_W2F) + tid * 8) = v;
}

// P1t f32 + P2 bf16 swizzled image [b][jt][row][h ^ ((row&15)<<3)]
__global__ void prep_p(const float* __restrict__ inp, const float* __restrict__ W1,
                       float* __restrict__ wsf) {
    int bn = blockIdx.x, h = threadIdx.x;
    const float* x = inp + (size_t)bn * 128;
    float a1 = 0.f, a2 = 0.f;
    for (int c = 0; c < 128; ++c) {
        float xv = x[c];
        a1 = fmaf(xv, W1[c * 256 + h], a1);
        a2 = fmaf(xv, W1[(128 + c) * 256 + h], a2);
    }
    float s1 = wsf[OFF_S1 + h], t1 = wsf[OFF_T1 + h];
    wsf[OFF_P1T + (size_t)bn * 256 + h] = a1 * s1 + t1;
    int b = bn >> 9, j = bn & 511, jt = j >> 6, row = j & 63;
    short* img = (short*)(wsf + OFF_P2I);
    img[(((b * 8 + jt) * 64 + row) << 8) + (h ^ ((row & 15) << 3))] = f2bf(a2 * s1);
}

__global__ __launch_bounds__(512, 4) void propmain(
    const float* __restrict__ adj, const float* __restrict__ wsf,
    float* __restrict__ out) {
    __shared__ __align__(16) short h1b[64 * 256];   // bf16 H1, &15-swizzled (32 KB)
    __shared__ __align__(16) short p2b[64 * 256];   // bf16 P2 tile, &15-swizzled (32 KB)
    __shared__ __align__(16) short adjbf[64 * 32];  // bf16 adj tile, chunk-XOR (4 KB)

    const int bi = blockIdx.x;
    const int b = bi >> 9;
    const int t = threadIdx.x;
    const int w = t >> 6, l = t & 63, r = l & 15, q = l >> 4;

    const float* P1t = wsf + OFF_P1T;
    const float* t2p = wsf + OFF_T2;
    const short* W1f = (const short*)(wsf + OFF_W1F);
    const short* W2f = (const short*)(wsf + OFF_W2F);
    const short* p2img = (const short*)(wsf + OFF_P2I) + ((size_t)b << 17);
    const float* adjbase = adj + (size_t)bi * 512 * 16;

    float t2v[2], p1v[2];
#pragma unroll
    for (int n = 0; n < 2; ++n) {
        const int hc = w * 32 + n * 16 + r;
        t2v[n] = t2p[hc];
        p1v[n] = P1t[(size_t)bi * 256 + hc];
    }

    // staging constants
    const int arow_st = t >> 3, ks_st = (t & 7) * 2;
    const int aslot = arow_st * 32 + (((ks_st >> 3) ^ (arow_st & 3)) << 3) + (ks_st & 7);
    // gload_lds: LDS dst wave-uniform (w,k); global src per-lane (+l*8)
    const short* p2src = p2img + w * 2048 + l * 8;  // + jt*16384 + k*512

    unsigned stadj;

#define STAGE_P2(JT) do {                                                       \
        const int _jt = (JT);                                                   \
        _Pragma("unroll")                                                       \
        for (int k = 0; k < 4; ++k)                                             \
            __builtin_amdgcn_global_load_lds(                                   \
                (const __attribute__((address_space(1))) unsigned*)             \
                    (p2src + _jt * 16384 + k * 512),                            \
                (__attribute__((address_space(3))) unsigned*)                   \
                    (p2b + w * 2048 + k * 512),                                 \
                16, 0, 0);                                                      \
    } while (0)

#define LOAD_ADJ(JT) do {                                                       \
        const float2 _av = *(const float2*)(adjbase + (JT) * 1024 + t * 2);     \
        stadj = pk2bf(_av.x, _av.y);                                            \
    } while (0)

    // prologue: zero adjbf pads, stage tile 0
    if (t < 256) {
        short8 z = {0, 0, 0, 0, 0, 0, 0, 0};
        *(short8*)(adjbf + t * 8) = z;
    }
    STAGE_P2(0);
    LOAD_ADJ(0);
    __syncthreads();   // zeros visible before adj data writes
    *(unsigned*)(adjbf + aslot) = stadj;

    float part[2] = {0.f, 0.f};

    for (int jt = 0; jt < 8; ++jt) {
        __syncthreads();  // (A) vmcnt(0) drain: p2b landed; adjbf writes visible

        if (jt < 7) LOAD_ADJ(jt + 1);  // global->reg, hides under phase 1

        // ---- phase 1: acc = P1 + adj@W1a (MFMA); epilogue += P2, relu -> h1b ----
        const short* w1fw = W1f + (w * 2) * 512 + l * 8;
        const short8 bB1_0 = *(const short8*)(w1fw);
        const short8 bB1_1 = *(const short8*)(w1fw + 512);
#pragma unroll
        for (int rf = 0; rf < 4; ++rf) {
            const int arow = rf * 16 + r;
            const short8 aA1 = *(const short8*)(adjbf + arow * 32 + (q ^ (r & 3)) * 8);
            f32x4 a0 = {p1v[0], p1v[0], p1v[0], p1v[0]};
            f32x4 a1 = {p1v[1], p1v[1], p1v[1], p1v[1]};
            a0 = __builtin_amdgcn_mfma_f32_16x16x32_bf16(aA1, bB1_0, a0, 0, 0, 0);
            a1 = __builtin_amdgcn_mfma_f32_16x16x32_bf16(aA1, bB1_1, a1, 0, 0, 0);
#pragma unroll
            for (int n = 0; n < 2; ++n) {
                const f32x4 av = n ? a1 : a0;
                const int colb = w * 32 + n * 16 + r;
#pragma unroll
                for (int e = 0; e < 4; ++e) {
                    const int row2 = rf * 16 + q * 4 + e;
                    const int slot = (row2 << 8) + (colb ^ ((row2 & 15) << 3));
                    const float y = fmaxf(av[e] + bf2f(p2b[slot]), 0.f);
                    h1b[slot] = f2bf(y);
                }
            }
        }
        __syncthreads();  // (B) h1b visible; p2b/adjbf reads of tile jt done

        if (jt < 7) {
            STAGE_P2(jt + 1);                    // async into p2b, flies over phase 2
            *(unsigned*)(adjbf + aslot) = stadj; // adj tile jt+1
        }

        // ---- phase 2: h1b @ W2 (frags loaded per s-step, blinded base) ----
        {
            const short* W2p = W2f + w * 8192 + l * 8;
            asm volatile("" : "+v"(W2p));  // opaque per tile: no hoist across jt
            f32x4 acc[4][2];
#pragma unroll
            for (int rf = 0; rf < 4; ++rf)
#pragma unroll
                for (int n = 0; n < 2; ++n)
                    acc[rf][n] = (f32x4){t2v[n], t2v[n], t2v[n], t2v[n]};
#pragma unroll
            for (int s = 0; s < 8; ++s) {
                const short8 f0 = *(const short8*)(W2p + s * 512);
                const short8 f1 = *(const short8*)(W2p + (8 + s) * 512);
#pragma unroll
                for (int rf = 0; rf < 4; ++rf) {
                    const int row = rf * 16 + r;
                    const short8 aA = *(const short8*)(
                        h1b + (row << 8) + ((s * 32 + q * 8) ^ ((row & 15) << 3)));
                    acc[rf][0] = __builtin_amdgcn_mfma_f32_16x16x32_bf16(
                        aA, f0, acc[rf][0], 0, 0, 0);
                    acc[rf][1] = __builtin_amdgcn_mfma_f32_16x16x32_bf16(
                        aA, f1, acc[rf][1], 0, 0, 0);
                }
            }
#pragma unroll
            for (int n = 0; n < 2; ++n) {
                float ps = 0.f;
#pragma unroll
                for (int rf = 0; rf < 4; ++rf)
#pragma unroll
                    for (int e = 0; e < 4; ++e) {
                        const float ex = exp2f(acc[rf][n][e]);
                        ps += __builtin_amdgcn_rcpf(ex + 1.f);
                    }
                part[n] += ps;
            }
        }
    }

    // sum_j tanh = 512 - 2*sum(rcp); reduce over q
#pragma unroll
    for (int n = 0; n < 2; ++n) {
        float v = part[n];
        v += __shfl_xor(v, 16, 64);
        v += __shfl_xor(v, 32, 64);
        if (q == 0) out[(size_t)bi * 256 + w * 32 + n * 16 + r] = 512.f - 2.f * v;
    }
#undef STAGE_P2
#undef LOAD_ADJ
}

extern "C" void kernel_launch(void* const* d_in, const int* in_sizes, int n_in,
                              void* d_out, int out_size, void* d_ws, size_t ws_size,
                              hipStream_t stream) {
    (void)in_sizes; (void)n_in; (void)out_size; (void)ws_size;
    const float* inputs = (const float*)d_in[0];
    const float* adj    = (const float*)d_in[1];
    const float* W1     = (const float*)d_in[2];
    const float* g1     = (const float*)d_in[3];
    const float* b1     = (const float*)d_in[4];
    const float* m1     = (const float*)d_in[5];
    const float* v1     = (const float*)d_in[6];
    const float* W2     = (const float*)d_in[7];
    const float* g2     = (const float*)d_in[8];
    const float* b2     = (const float*)d_in[9];
    const float* m2     = (const float*)d_in[10];
    const float* v2     = (const float*)d_in[11];
    float* out = (float*)d_out;
    float* wsf = (float*)d_ws;

    prep_scalars<<<1, 256, 0, stream>>>(g1, b1, m1, v1, g2, b2, m2, v2, wsf);
    prep_w1f<<<4, 256, 0, stream>>>(W1, wsf);
    prep_w2f<<<32, 256, 0, stream>>>(W2, g2, v2, wsf);
    prep_p<<<1024, 256, 0, stream>>>(inputs, W1, wsf);
    propmain<<<1024, 512, 0, stream>>>(adj, wsf, out);
}